// Round 9
// baseline (677.574 us; speedup 1.0000x reference)
//
#include <hip/hip_runtime.h>
#include <math.h>

#define NN 50000
#define EE 400000
#define FIN 128
#define HH 256
#define BN_EPS 1e-5f
#define NSB 196   // scan blocks = ceil(NN/256)

typedef __attribute__((ext_vector_type(8))) short short8v;
typedef __attribute__((ext_vector_type(4))) short short4v;
typedef __attribute__((ext_vector_type(2))) short short2v;
typedef __attribute__((ext_vector_type(4))) float f32x4;

__device__ inline short f2bf(float x) {
    union { float f; unsigned u; } c; c.f = x;
    unsigned r = c.u + 0x7FFF + ((c.u >> 16) & 1);   // RNE
    return (short)(r >> 16);
}
__device__ inline float bf2f(short b) {
    union { unsigned u; float f; } c; c.u = ((unsigned)(unsigned short)b) << 16;
    return c.f;
}

// ---------------- graph prep ----------------

__global__ void k_count(const int* __restrict__ dst, int* __restrict__ cnt) {
    int e = blockIdx.x * 256 + threadIdx.x;
    if (e < EE) atomicAdd(&cnt[dst[e]], 1);
}

__global__ __launch_bounds__(256) void k_scan1(const int* __restrict__ cnt,
                                               int* __restrict__ bsum) {
    __shared__ int ws4[4];
    int i = blockIdx.x * 256 + threadIdx.x;
    int s = (i < NN) ? cnt[i] : 0;
#pragma unroll
    for (int o = 32; o; o >>= 1) s += __shfl_down(s, o);
    if ((threadIdx.x & 63) == 0) ws4[threadIdx.x >> 6] = s;
    __syncthreads();
    if (threadIdx.x == 0) bsum[blockIdx.x] = ws4[0] + ws4[1] + ws4[2] + ws4[3];
}

__global__ __launch_bounds__(256) void k_scan2(const int* __restrict__ bsum,
                                               int* __restrict__ boff,
                                               int* __restrict__ row_start) {
    __shared__ int sh[256];
    int t = threadIdx.x;
    int v = (t < NSB) ? bsum[t] : 0;
    sh[t] = v;
    __syncthreads();
    for (int o = 1; o < 256; o <<= 1) {
        int u = (t >= o) ? sh[t - o] : 0;
        __syncthreads();
        sh[t] += u;
        __syncthreads();
    }
    if (t < NSB) boff[t] = sh[t] - v;   // exclusive
    if (t == 0) row_start[NN] = EE;
}

__global__ __launch_bounds__(256) void k_scan3(const int* __restrict__ cnt,
                                               const int* __restrict__ boff,
                                               int* __restrict__ row_start,
                                               int* __restrict__ cursor,
                                               float* __restrict__ dinv) {
    __shared__ int sh[256];
    int t = threadIdx.x;
    int i = blockIdx.x * 256 + t;
    int v = (i < NN) ? cnt[i] : 0;
    sh[t] = v;
    __syncthreads();
    for (int o = 1; o < 256; o <<= 1) {
        int u = (t >= o) ? sh[t - o] : 0;
        __syncthreads();
        sh[t] += u;
        __syncthreads();
    }
    if (i < NN) {
        int rs = boff[blockIdx.x] + sh[t] - v;
        row_start[i] = rs;
        cursor[i] = rs;
        dinv[i] = rsqrtf((float)(v + 1));
    }
}

// CSR stores the ORIGINAL EDGE ID; src is re-read via src[eid] (L2-resident)
__global__ void k_fill(const int* __restrict__ dst,
                       int* __restrict__ cursor, int* __restrict__ csr_eid) {
    int e = blockIdx.x * 256 + threadIdx.x;
    if (e < EE) {
        int pos = atomicAdd(&cursor[dst[e]], 1);
        csr_eid[pos] = e;
    }
}

// ---------------- operand prep ----------------

// split fp32 W [K][NC] row-major -> hi/lo bf16 in k-group-major layout [K/8][NC][8]
__global__ void k_wsplit(const float* __restrict__ src, short* __restrict__ hi,
                         short* __restrict__ lo, int K, int NC) {
    int i = blockIdx.x * 256 + threadIdx.x;
    if (i >= K * NC) return;
    int k = i / NC, n = i - k * NC;
    float v = src[i];
    short h = f2bf(v);
    short lw = f2bf(v - bf2f(h));
    size_t d = ((size_t)(k >> 3) * NC + n) * 8 + (k & 7);
    hi[d] = h;
    lo[d] = lw;
}

// Wcat[k][c] (256x512) = [Wm1_top | Wm1_bot] -> hi/lo k-group-major
__global__ void k_wsplit_cat(const float* __restrict__ Wm1, short* __restrict__ hi,
                             short* __restrict__ lo) {
    int i = blockIdx.x * 256 + threadIdx.x;
    if (i >= 256 * 512) return;
    int k = i >> 9, c = i & 511;
    float v = (c < 256) ? Wm1[k * 256 + c] : Wm1[(256 + k) * 256 + (c - 256)];
    short h = f2bf(v);
    short lw = f2bf(v - bf2f(h));
    size_t d = ((size_t)(k >> 3) * 512 + c) * 8 + (k & 7);
    hi[d] = h;
    lo[d] = lw;
}

// ---------------- aggregation (gather) kernels, one wave per node ----------------

// G1 = dinv[n]*(dinv[n]*x[n] + sum_j dinv[j]*x[j]) -> bf16 hi/lo  (128-dim)
__global__ __launch_bounds__(256) void k_aggX(const float* __restrict__ x,
                                              const int* __restrict__ srcl,
                                              const int* __restrict__ csr_eid,
                                              const int* __restrict__ row_start,
                                              const float* __restrict__ dinv,
                                              short* __restrict__ Ghi,
                                              short* __restrict__ Glo) {
    int wave = threadIdx.x >> 6, lane = threadIdx.x & 63;
    int n = blockIdx.x * 4 + wave;
    if (n >= NN) return;
    const float2* base = reinterpret_cast<const float2*>(x);
    float g = dinv[n];
    float2 v = base[(size_t)n * 64 + lane];
    v.x *= g; v.y *= g;
    int s0 = row_start[n], s1 = row_start[n + 1];
    for (int j = s0; j < s1; ++j) {
        int sj = srcl[csr_eid[j]];
        float gj = dinv[sj];
        float2 u = base[(size_t)sj * 64 + lane];
        v.x += gj * u.x; v.y += gj * u.y;
    }
    v.x *= g; v.y *= g;
    short2v h, lw;
    short h0 = f2bf(v.x), h1 = f2bf(v.y);
    h[0] = h0; h[1] = h1;
    lw[0] = f2bf(v.x - bf2f(h0)); lw[1] = f2bf(v.y - bf2f(h1));
    *(short2v*)(Ghi + (size_t)n * FIN + lane * 2) = h;
    *(short2v*)(Glo + (size_t)n * FIN + lane * 2) = lw;
}

// G2 = dinv[n]*(T[n] + sum T[j]) -> bf16 hi/lo   (256-dim; T pre-scaled by dinv)
__global__ __launch_bounds__(256) void k_aggH(const float* __restrict__ T,
                                              const int* __restrict__ srcl,
                                              const int* __restrict__ csr_eid,
                                              const int* __restrict__ row_start,
                                              const float* __restrict__ dinv,
                                              short* __restrict__ Ghi,
                                              short* __restrict__ Glo) {
    int wave = threadIdx.x >> 6, lane = threadIdx.x & 63;
    int n = blockIdx.x * 4 + wave;
    if (n >= NN) return;
    const float4* base = reinterpret_cast<const float4*>(T);
    float4 v = base[(size_t)n * 64 + lane];
    int s0 = row_start[n], s1 = row_start[n + 1];
    for (int j = s0; j < s1; ++j) {
        int sj = srcl[csr_eid[j]];
        float4 u = base[(size_t)sj * 64 + lane];
        v.x += u.x; v.y += u.y; v.z += u.z; v.w += u.w;
    }
    float g = dinv[n];
    float o[4] = {v.x * g, v.y * g, v.z * g, v.w * g};
    short4v h, lw;
#pragma unroll
    for (int j = 0; j < 4; ++j) {
        short hh = f2bf(o[j]);
        h[j] = hh;
        lw[j] = f2bf(o[j] - bf2f(hh));
    }
    *(short4v*)(Ghi + (size_t)n * HH + lane * 4) = h;
    *(short4v*)(Glo + (size_t)n * HH + lane * 4) = lw;
}

// ---------------- bf16-split MFMA stripe GEMM (BM=32) ----------------
// One block per 32-row stripe; A panel (hi+lo, full K) in LDS (32KB @ K=256);
// 4 waves each own a 32-col slice -> 128 cols per pass. B [K/8][NC][8] hi/lo.
// EPI: 0 = +bias fp32 out. 1 = +bias relu bf16 hi/lo. 2 = bf16 out, split halves.

template<int K, int NC, int EPI>
__global__ __launch_bounds__(256, 4) void gemm_stripe(
    const short* __restrict__ Ahi, const short* __restrict__ Alo,
    const short* __restrict__ Bthi, const short* __restrict__ Btlo,
    const float* __restrict__ bias,
    float* __restrict__ OutF, short* __restrict__ OutH, short* __restrict__ OutL,
    short* __restrict__ OutA, short* __restrict__ OutB2, int M)
{
    constexpr int NKT = K / 32;
    constexpr int NSLAB = K / 8;
    constexpr int NPASS = NC / 128;
    __shared__ short lds[2 * NSLAB * 32 * 8];
    const int tid = threadIdx.x;
    const int w = tid >> 6, l = tid & 63;
    const int m0 = blockIdx.x * 32;
    const int lhi = l >> 4, llo = l & 15;

    // stage A panel: [buf][kgrp][row 0..31][8], row-fastest (conflict-free LDS writes)
    for (int idx = tid; idx < 2 * NSLAB * 32; idx += 256) {
        int buf = (idx >= NSLAB * 32) ? 1 : 0;
        int rem = idx - buf * (NSLAB * 32);
        int kg = rem >> 5, row = rem & 31;
        const short* srcp = buf ? Alo : Ahi;
        int r = m0 + row;
        if (r > M - 1) r = M - 1;
        short8v v = *(const short8v*)(srcp + (size_t)r * K + kg * 8);
        *(short8v*)(&lds[idx * 8]) = v;
    }
    __syncthreads();

    for (int pass = 0; pass < NPASS; ++pass) {
        const int n0 = pass * 128 + w * 32;
        f32x4 acc[2][2] = {};
#pragma unroll
        for (int kt = 0; kt < NKT; ++kt) {
            short8v bh[2], bl[2];
#pragma unroll
            for (int nt = 0; nt < 2; ++nt) {
                size_t idx = ((size_t)(kt * 4 + lhi) * NC + (n0 + nt * 16 + llo)) * 8;
                bh[nt] = *(const short8v*)(Bthi + idx);
                bl[nt] = *(const short8v*)(Btlo + idx);
            }
            short8v ah[2], al[2];
#pragma unroll
            for (int mt = 0; mt < 2; ++mt) {
                int off = ((kt * 4 + lhi) * 32 + mt * 16 + llo) * 8;
                ah[mt] = *(const short8v*)(&lds[off]);
                al[mt] = *(const short8v*)(&lds[off + NSLAB * 32 * 8]);
            }
#pragma unroll
            for (int mt = 0; mt < 2; ++mt)
#pragma unroll
                for (int nt = 0; nt < 2; ++nt) {
                    acc[mt][nt] = __builtin_amdgcn_mfma_f32_16x16x32_bf16(ah[mt], bh[nt], acc[mt][nt], 0, 0, 0);
                    acc[mt][nt] = __builtin_amdgcn_mfma_f32_16x16x32_bf16(ah[mt], bl[nt], acc[mt][nt], 0, 0, 0);
                    acc[mt][nt] = __builtin_amdgcn_mfma_f32_16x16x32_bf16(al[mt], bh[nt], acc[mt][nt], 0, 0, 0);
                }
        }
        // epilogue: C/D col = lane&15, row = (lane>>4)*4 + r
#pragma unroll
        for (int mt = 0; mt < 2; ++mt)
#pragma unroll
            for (int r = 0; r < 4; ++r) {
                int gm = m0 + mt * 16 + lhi * 4 + r;
                if (gm >= M) continue;
#pragma unroll
                for (int nt = 0; nt < 2; ++nt) {
                    int col = n0 + nt * 16 + llo;
                    float v = acc[mt][nt][r];
                    if constexpr (EPI == 0) {
                        OutF[(size_t)gm * NC + col] = v + bias[col];
                    } else if constexpr (EPI == 1) {
                        float o = fmaxf(v + bias[col], 0.0f);
                        short h = f2bf(o);
                        OutH[(size_t)gm * NC + col] = h;
                        OutL[(size_t)gm * NC + col] = f2bf(o - bf2f(h));
                    } else {
                        short h = f2bf(v);
                        if (col < NC / 2)
                            OutA[(size_t)gm * (NC / 2) + col] = h;
                        else
                            OutB2[(size_t)gm * (NC / 2) + col - NC / 2] = h;
                    }
                }
            }
    }
}

// ---------------- BatchNorm ----------------

__global__ __launch_bounds__(256) void k_bn_stats(const float* __restrict__ Hm,
                                                  float* __restrict__ ssum,
                                                  float* __restrict__ ssq) {
    int c = threadIdx.x;
    int r0 = blockIdx.x * 64;
    int r1 = min(r0 + 64, NN);
    float s = 0.f, q = 0.f;
    for (int r = r0; r < r1; ++r) {
        float v = Hm[(size_t)r * HH + c];
        s += v;
        q += v * v;
    }
    atomicAdd(&ssum[c], s);
    atomicAdd(&ssq[c], q);
}

__global__ void k_bn_final(const float* __restrict__ ssum, const float* __restrict__ ssq,
                           const float* __restrict__ gamma, const float* __restrict__ beta,
                           float* __restrict__ scale, float* __restrict__ shift) {
    int c = threadIdx.x;
    float mu = ssum[c] / (float)NN;
    float var = ssq[c] / (float)NN - mu * mu;
    float rstd = rsqrtf(var + BN_EPS);
    float sc = rstd * gamma[c];
    scale[c] = sc;
    shift[c] = beta[c] - mu * sc;
}

// T = dinv_row * relu(scale*P1 + shift)
__global__ void k_bn_apply_T(const float* __restrict__ P1, const float* __restrict__ scale,
                             const float* __restrict__ shift, const float* __restrict__ dinv,
                             float* __restrict__ T) {
    int i4 = blockIdx.x * 256 + threadIdx.x;
    if (i4 >= NN * HH / 4) return;
    int c4 = i4 & 63;
    float g = dinv[i4 >> 6];
    float4 v = reinterpret_cast<const float4*>(P1)[i4];
    float4 sc = reinterpret_cast<const float4*>(scale)[c4];
    float4 sh = reinterpret_cast<const float4*>(shift)[c4];
    v.x = g * fmaxf(v.x * sc.x + sh.x, 0.f);
    v.y = g * fmaxf(v.y * sc.y + sh.y, 0.f);
    v.z = g * fmaxf(v.z * sc.z + sh.z, 0.f);
    v.w = g * fmaxf(v.w * sc.w + sh.w, 0.f);
    reinterpret_cast<float4*>(T)[i4] = v;
}

// ---------------- edge head (dst-centric): one wave per node ----------------
// out[e] = sigmoid(relu(A[src]+B[dst]+bm1).Wm2 + bm2); B-side hoisted per node.

__global__ __launch_bounds__(256) void k_edge_csr(const short* __restrict__ Aarr,
                                                  const short* __restrict__ Barr,
                                                  const int* __restrict__ srcl,
                                                  const int* __restrict__ csr_eid,
                                                  const int* __restrict__ row_start,
                                                  const float* __restrict__ bm1,
                                                  const float* __restrict__ Wm2,
                                                  const float* __restrict__ bm2,
                                                  float* __restrict__ out) {
    int wave = threadIdx.x >> 6;
    int lane = threadIdx.x & 63;
    int n = blockIdx.x * 4 + wave;
    if (n >= NN) return;
    float4 bb = reinterpret_cast<const float4*>(bm1)[lane];
    float4 w = reinterpret_cast<const float4*>(Wm2)[lane];
    short4v bv = *(const short4v*)(Barr + (size_t)n * 256 + lane * 4);
    float b0 = bf2f(bv[0]) + bb.x, b1 = bf2f(bv[1]) + bb.y,
          b2 = bf2f(bv[2]) + bb.z, b3 = bf2f(bv[3]) + bb.w;
    float zb = bm2[0];
    int s0 = row_start[n], s1 = row_start[n + 1];
    for (int j = s0; j < s1; ++j) {
        int e = csr_eid[j];
        int s = srcl[e];
        short4v a = *(const short4v*)(Aarr + (size_t)s * 256 + lane * 4);
        float t = fmaxf(bf2f(a[0]) + b0, 0.f) * w.x
                + fmaxf(bf2f(a[1]) + b1, 0.f) * w.y
                + fmaxf(bf2f(a[2]) + b2, 0.f) * w.z
                + fmaxf(bf2f(a[3]) + b3, 0.f) * w.w;
#pragma unroll
        for (int off = 32; off; off >>= 1) t += __shfl_xor(t, off);
        if (lane == 0) out[e] = 1.0f / (1.0f + expf(-(t + zb)));
    }
}

// ---------------- launch ----------------

extern "C" void kernel_launch(void* const* d_in, const int* in_sizes, int n_in,
                              void* d_out, int out_size, void* d_ws, size_t ws_size,
                              hipStream_t stream) {
    const float* x     = (const float*)d_in[0];
    const int*   ei    = (const int*)d_in[1];
    const float* W1    = (const float*)d_in[2];
    const float* b1    = (const float*)d_in[3];
    const float* gamma = (const float*)d_in[4];
    const float* beta  = (const float*)d_in[5];
    const float* W2    = (const float*)d_in[6];
    const float* b2    = (const float*)d_in[7];
    const float* Wm1   = (const float*)d_in[8];
    const float* bm1   = (const float*)d_in[9];
    const float* Wm2   = (const float*)d_in[10];
    const float* bm2   = (const float*)d_in[11];
    float* out = (float*)d_out;
    const int* src = ei;
    const int* dst = ei + EE;

    char* ws = (char*)d_ws;
    size_t off = 0;
    auto take = [&](size_t b) -> char* {
        char* p = ws + off;
        off += (b + 255) & ~(size_t)255;
        return p;
    };
    // small tables (~3.3 MB)
    int*   deg_cnt   = (int*)take((size_t)NN * 4);
    float* dinv      = (float*)take((size_t)NN * 4);
    int*   row_start = (int*)take((size_t)(NN + 1) * 4);
    int*   cursor    = (int*)take((size_t)NN * 4);
    int*   csr_eid   = (int*)take((size_t)EE * 4);
    int*   bsum      = (int*)take((size_t)NSB * 4);
    int*   boff      = (int*)take((size_t)NSB * 4);
    float* ssum      = (float*)take(1024);
    float* ssq       = (float*)take(1024);
    float* scale     = (float*)take(1024);
    float* shift     = (float*)take(1024);
    short* W1thi     = (short*)take((size_t)128 * 256 * 2);
    short* W1tlo     = (short*)take((size_t)128 * 256 * 2);
    short* W2thi     = (short*)take((size_t)256 * 256 * 2);
    short* W2tlo     = (short*)take((size_t)256 * 256 * 2);
    short* Wcthi     = (short*)take((size_t)256 * 512 * 2);
    short* Wctlo     = (short*)take((size_t)256 * 512 * 2);
    // three 51.2 MB slots, liveness-aliased (peak ~157 MB, known to fit)
    const size_t SLOT = (size_t)NN * HH * 4;  // 51,200,000
    char* slotA = take(SLOT);
    char* slotB = take(SLOT);
    char* slotC = take(SLOT);

    short* G1hi = (short*)slotB;                    // [N,128] bf16
    short* G1lo = (short*)(slotB + 12800000);
    float* P1   = (float*)slotC;                    // [N,256] fp32
    float* T    = (float*)slotA;                    // [N,256] fp32
    short* G2hi = (short*)slotB;                    // [N,256] bf16 (G1 dead)
    short* G2lo = (short*)(slotB + 25600000);
    short* H2hi = (short*)slotC;                    // [N,256] bf16 (P1 dead)
    short* H2lo = (short*)(slotC + 25600000);
    short* Aarr = (short*)slotA;                    // [N,256] bf16 (T dead)
    short* Barr = (short*)(slotA + 25600000);
    (void)ssq; (void)ws_size;

    hipMemsetAsync(deg_cnt, 0, (size_t)NN * 4, stream);
    hipMemsetAsync(ssum, 0, 2048, stream);  // ssum + ssq adjacent

    k_count<<<(EE + 255) / 256, 256, 0, stream>>>(dst, deg_cnt);
    k_scan1<<<NSB, 256, 0, stream>>>(deg_cnt, bsum);
    k_scan2<<<1, 256, 0, stream>>>(bsum, boff, row_start);
    k_scan3<<<NSB, 256, 0, stream>>>(deg_cnt, boff, row_start, cursor, dinv);
    k_fill<<<(EE + 255) / 256, 256, 0, stream>>>(dst, cursor, csr_eid);
    k_wsplit<<<(128 * 256 + 255) / 256, 256, 0, stream>>>(W1, W1thi, W1tlo, 128, 256);
    k_wsplit<<<(256 * 256 + 255) / 256, 256, 0, stream>>>(W2, W2thi, W2tlo, 256, 256);
    k_wsplit_cat<<<(256 * 512 + 255) / 256, 256, 0, stream>>>(Wm1, Wcthi, Wctlo);

    const int MB32 = (NN + 31) / 32;  // 1563
    // layer 1 (aggregate-first, scale fused)
    k_aggX<<<(NN + 3) / 4, 256, 0, stream>>>(x, src, csr_eid, row_start, dinv, G1hi, G1lo);
    gemm_stripe<128, 256, 0><<<MB32, 256, 0, stream>>>(G1hi, G1lo, W1thi, W1tlo, b1,
                                                       P1, nullptr, nullptr, nullptr, nullptr, NN);
    // batchnorm; T = dinv * relu(BN(P1))
    k_bn_stats<<<(NN + 63) / 64, 256, 0, stream>>>(P1, ssum, ssq);
    k_bn_final<<<1, 256, 0, stream>>>(ssum, ssq, gamma, beta, scale, shift);
    k_bn_apply_T<<<NN * HH / 4 / 256, 256, 0, stream>>>(P1, scale, shift, dinv, T);
    // layer 2
    k_aggH<<<(NN + 3) / 4, 256, 0, stream>>>(T, src, csr_eid, row_start, dinv, G2hi, G2lo);
    gemm_stripe<256, 256, 1><<<MB32, 256, 0, stream>>>(G2hi, G2lo, W2thi, W2tlo, b2,
                                                       nullptr, H2hi, H2lo, nullptr, nullptr, NN);
    // edge-head node factors: [Aarr | Barr] = H2 @ Wcat (bf16 out)
    gemm_stripe<256, 512, 2><<<MB32, 256, 0, stream>>>(H2hi, H2lo, Wcthi, Wctlo, nullptr,
                                                       nullptr, nullptr, nullptr, Aarr, Barr, NN);
    // edge head (dst-centric)
    k_edge_csr<<<(NN + 3) / 4, 256, 0, stream>>>(Aarr, Barr, src, csr_eid, row_start,
                                                 bm1, Wm2, bm2, out);
}

// Round 10
// 664.250 us; speedup vs baseline: 1.0201x; 1.0201x over previous
//
#include <hip/hip_runtime.h>
#include <math.h>

#define NN 50000
#define EE 400000
#define FIN 128
#define HH 256
#define BN_EPS 1e-5f
#define NSB 196   // scan blocks = ceil(NN/256)

typedef __attribute__((ext_vector_type(8))) short short8v;
typedef __attribute__((ext_vector_type(4))) short short4v;
typedef __attribute__((ext_vector_type(2))) short short2v;
typedef __attribute__((ext_vector_type(4))) float f32x4;

__device__ inline short f2bf(float x) {
    union { float f; unsigned u; } c; c.f = x;
    unsigned r = c.u + 0x7FFF + ((c.u >> 16) & 1);   // RNE
    return (short)(r >> 16);
}
__device__ inline float bf2f(short b) {
    union { unsigned u; float f; } c; c.u = ((unsigned)(unsigned short)b) << 16;
    return c.f;
}

// ---------------- graph prep ----------------

__global__ void k_count(const int* __restrict__ dst, int* __restrict__ cnt) {
    int e = blockIdx.x * 256 + threadIdx.x;
    if (e < EE) atomicAdd(&cnt[dst[e]], 1);
}

__global__ __launch_bounds__(256) void k_scan1(const int* __restrict__ cnt,
                                               int* __restrict__ bsum) {
    __shared__ int ws4[4];
    int i = blockIdx.x * 256 + threadIdx.x;
    int s = (i < NN) ? cnt[i] : 0;
#pragma unroll
    for (int o = 32; o; o >>= 1) s += __shfl_down(s, o);
    if ((threadIdx.x & 63) == 0) ws4[threadIdx.x >> 6] = s;
    __syncthreads();
    if (threadIdx.x == 0) bsum[blockIdx.x] = ws4[0] + ws4[1] + ws4[2] + ws4[3];
}

__global__ __launch_bounds__(256) void k_scan2(const int* __restrict__ bsum,
                                               int* __restrict__ boff,
                                               int* __restrict__ row_start) {
    __shared__ int sh[256];
    int t = threadIdx.x;
    int v = (t < NSB) ? bsum[t] : 0;
    sh[t] = v;
    __syncthreads();
    for (int o = 1; o < 256; o <<= 1) {
        int u = (t >= o) ? sh[t - o] : 0;
        __syncthreads();
        sh[t] += u;
        __syncthreads();
    }
    if (t < NSB) boff[t] = sh[t] - v;   // exclusive
    if (t == 0) row_start[NN] = EE;
}

__global__ __launch_bounds__(256) void k_scan3(const int* __restrict__ cnt,
                                               const int* __restrict__ boff,
                                               int* __restrict__ row_start,
                                               int* __restrict__ cursor,
                                               float* __restrict__ dinv) {
    __shared__ int sh[256];
    int t = threadIdx.x;
    int i = blockIdx.x * 256 + t;
    int v = (i < NN) ? cnt[i] : 0;
    sh[t] = v;
    __syncthreads();
    for (int o = 1; o < 256; o <<= 1) {
        int u = (t >= o) ? sh[t - o] : 0;
        __syncthreads();
        sh[t] += u;
        __syncthreads();
    }
    if (i < NN) {
        int rs = boff[blockIdx.x] + sh[t] - v;
        row_start[i] = rs;
        cursor[i] = rs;
        dinv[i] = rsqrtf((float)(v + 1));
    }
}

// CSR stores the ORIGINAL EDGE ID; src is re-read via src[eid] (L2-resident)
__global__ void k_fill(const int* __restrict__ dst,
                       int* __restrict__ cursor, int* __restrict__ csr_eid) {
    int e = blockIdx.x * 256 + threadIdx.x;
    if (e < EE) {
        int pos = atomicAdd(&cursor[dst[e]], 1);
        csr_eid[pos] = e;
    }
}

// ---------------- operand prep ----------------

// split fp32 W [K][NC] row-major -> hi/lo bf16 in k-group-major layout [K/8][NC][8]
__global__ void k_wsplit(const float* __restrict__ src, short* __restrict__ hi,
                         short* __restrict__ lo, int K, int NC) {
    int i = blockIdx.x * 256 + threadIdx.x;
    if (i >= K * NC) return;
    int k = i / NC, n = i - k * NC;
    float v = src[i];
    short h = f2bf(v);
    short lw = f2bf(v - bf2f(h));
    size_t d = ((size_t)(k >> 3) * NC + n) * 8 + (k & 7);
    hi[d] = h;
    lo[d] = lw;
}

// Wcat[k][c] (256x512) = [Wm1_top | Wm1_bot] -> hi/lo k-group-major
__global__ void k_wsplit_cat(const float* __restrict__ Wm1, short* __restrict__ hi,
                             short* __restrict__ lo) {
    int i = blockIdx.x * 256 + threadIdx.x;
    if (i >= 256 * 512) return;
    int k = i >> 9, c = i & 511;
    float v = (c < 256) ? Wm1[k * 256 + c] : Wm1[(256 + k) * 256 + (c - 256)];
    short h = f2bf(v);
    short lw = f2bf(v - bf2f(h));
    size_t d = ((size_t)(k >> 3) * 512 + c) * 8 + (k & 7);
    hi[d] = h;
    lo[d] = lw;
}

// ---------------- aggregation (gather) kernels, one wave per node ----------------

// G1 = dinv[n]*(dinv[n]*x[n] + sum_j dinv[j]*x[j]) -> bf16 hi/lo  (128-dim)
__global__ __launch_bounds__(256) void k_aggX(const float* __restrict__ x,
                                              const int* __restrict__ srcl,
                                              const int* __restrict__ csr_eid,
                                              const int* __restrict__ row_start,
                                              const float* __restrict__ dinv,
                                              short* __restrict__ Ghi,
                                              short* __restrict__ Glo) {
    int wave = threadIdx.x >> 6, lane = threadIdx.x & 63;
    int n = blockIdx.x * 4 + wave;
    if (n >= NN) return;
    const float2* base = reinterpret_cast<const float2*>(x);
    float g = dinv[n];
    float2 v = base[(size_t)n * 64 + lane];
    v.x *= g; v.y *= g;
    int s0 = row_start[n], s1 = row_start[n + 1];
    for (int j = s0; j < s1; ++j) {
        int sj = srcl[csr_eid[j]];
        float gj = dinv[sj];
        float2 u = base[(size_t)sj * 64 + lane];
        v.x += gj * u.x; v.y += gj * u.y;
    }
    v.x *= g; v.y *= g;
    short2v h, lw;
    short h0 = f2bf(v.x), h1 = f2bf(v.y);
    h[0] = h0; h[1] = h1;
    lw[0] = f2bf(v.x - bf2f(h0)); lw[1] = f2bf(v.y - bf2f(h1));
    *(short2v*)(Ghi + (size_t)n * FIN + lane * 2) = h;
    *(short2v*)(Glo + (size_t)n * FIN + lane * 2) = lw;
}

// G2 = dinv[n]*(T[n] + sum T[j]) -> bf16 hi/lo   (256-dim; T pre-scaled by dinv)
__global__ __launch_bounds__(256) void k_aggH(const float* __restrict__ T,
                                              const int* __restrict__ srcl,
                                              const int* __restrict__ csr_eid,
                                              const int* __restrict__ row_start,
                                              const float* __restrict__ dinv,
                                              short* __restrict__ Ghi,
                                              short* __restrict__ Glo) {
    int wave = threadIdx.x >> 6, lane = threadIdx.x & 63;
    int n = blockIdx.x * 4 + wave;
    if (n >= NN) return;
    const float4* base = reinterpret_cast<const float4*>(T);
    float4 v = base[(size_t)n * 64 + lane];
    int s0 = row_start[n], s1 = row_start[n + 1];
    for (int j = s0; j < s1; ++j) {
        int sj = srcl[csr_eid[j]];
        float4 u = base[(size_t)sj * 64 + lane];
        v.x += u.x; v.y += u.y; v.z += u.z; v.w += u.w;
    }
    float g = dinv[n];
    float o[4] = {v.x * g, v.y * g, v.z * g, v.w * g};
    short4v h, lw;
#pragma unroll
    for (int j = 0; j < 4; ++j) {
        short hh = f2bf(o[j]);
        h[j] = hh;
        lw[j] = f2bf(o[j] - bf2f(hh));
    }
    *(short4v*)(Ghi + (size_t)n * HH + lane * 4) = h;
    *(short4v*)(Glo + (size_t)n * HH + lane * 4) = lw;
}

// ---------------- bf16-split MFMA stripe GEMM (BM=64, 8 waves) ----------------
// One block per 64-row stripe, 512 threads = 8 waves arranged wr(2) x wc(4);
// wr-pairs with equal wc read IDENTICAL B fragments (L1 share). A panel (hi+lo,
// full K) staged to LDS once (64KB @ K=256 -> 2 blocks/CU = 16 waves/CU).
// Passes cover 128 cols each. B in [K/8][NC][8] hi/lo layout (L2-resident).
// EPI: 0 = +bias fp32 out. 1 = +bias relu bf16 hi/lo. 2 = bf16 out, split halves.

template<int K, int NC, int EPI>
__global__ __launch_bounds__(512, 4) void gemm_stripe(
    const short* __restrict__ Ahi, const short* __restrict__ Alo,
    const short* __restrict__ Bthi, const short* __restrict__ Btlo,
    const float* __restrict__ bias,
    float* __restrict__ OutF, short* __restrict__ OutH, short* __restrict__ OutL,
    short* __restrict__ OutA, short* __restrict__ OutB2, int M)
{
    constexpr int NKT = K / 32;
    constexpr int NSLAB = K / 8;
    constexpr int NPASS = NC / 128;
    __shared__ short lds[2 * NSLAB * 512];
    const int tid = threadIdx.x;
    const int w = tid >> 6, l = tid & 63;
    const int wr = w >> 2, wc = w & 3;
    const int m0 = blockIdx.x * 64;
    const int lhi = l >> 4, llo = l & 15;

    // stage A panel (hi then lo): slab s -> kgrp s%NSLAB, lane = row (64 rows)
    for (int s = w; s < 2 * NSLAB; s += 8) {
        int kg = (s < NSLAB) ? s : (s - NSLAB);
        const short* srcp = (s < NSLAB) ? Ahi : Alo;
        int row = m0 + l;
        if (row > M - 1) row = M - 1;
        short8v v = *(const short8v*)(srcp + (size_t)row * K + kg * 8);
        *(short8v*)(&lds[s * 512 + l * 8]) = v;
    }
    __syncthreads();

    for (int pass = 0; pass < NPASS; ++pass) {
        const int n0 = pass * 128 + wc * 32;
        f32x4 acc[2][2] = {};
#pragma unroll
        for (int kt = 0; kt < NKT; ++kt) {
            short8v bh[2], bl[2];
#pragma unroll
            for (int nt = 0; nt < 2; ++nt) {
                size_t idx = ((size_t)(kt * 4 + lhi) * NC + (n0 + nt * 16 + llo)) * 8;
                bh[nt] = *(const short8v*)(Bthi + idx);
                bl[nt] = *(const short8v*)(Btlo + idx);
            }
            short8v ah[2], al[2];
#pragma unroll
            for (int mt = 0; mt < 2; ++mt) {
                int off = (kt * 4 + lhi) * 512 + (wr * 32 + mt * 16 + llo) * 8;
                ah[mt] = *(const short8v*)(&lds[off]);
                al[mt] = *(const short8v*)(&lds[off + NSLAB * 512]);
            }
#pragma unroll
            for (int mt = 0; mt < 2; ++mt)
#pragma unroll
                for (int nt = 0; nt < 2; ++nt) {
                    acc[mt][nt] = __builtin_amdgcn_mfma_f32_16x16x32_bf16(ah[mt], bh[nt], acc[mt][nt], 0, 0, 0);
                    acc[mt][nt] = __builtin_amdgcn_mfma_f32_16x16x32_bf16(ah[mt], bl[nt], acc[mt][nt], 0, 0, 0);
                    acc[mt][nt] = __builtin_amdgcn_mfma_f32_16x16x32_bf16(al[mt], bh[nt], acc[mt][nt], 0, 0, 0);
                }
        }
        // epilogue: C/D col = lane&15, row = (lane>>4)*4 + r
#pragma unroll
        for (int mt = 0; mt < 2; ++mt)
#pragma unroll
            for (int r = 0; r < 4; ++r) {
                int gm = m0 + wr * 32 + mt * 16 + lhi * 4 + r;
                if (gm >= M) continue;
#pragma unroll
                for (int nt = 0; nt < 2; ++nt) {
                    int col = pass * 128 + wc * 32 + nt * 16 + llo;
                    float v = acc[mt][nt][r];
                    if constexpr (EPI == 0) {
                        OutF[(size_t)gm * NC + col] = v + bias[col];
                    } else if constexpr (EPI == 1) {
                        float o = fmaxf(v + bias[col], 0.0f);
                        short h = f2bf(o);
                        OutH[(size_t)gm * NC + col] = h;
                        OutL[(size_t)gm * NC + col] = f2bf(o - bf2f(h));
                    } else {
                        short h = f2bf(v);
                        if (col < NC / 2)
                            OutA[(size_t)gm * (NC / 2) + col] = h;
                        else
                            OutB2[(size_t)gm * (NC / 2) + col - NC / 2] = h;
                    }
                }
            }
    }
}

// ---------------- BatchNorm ----------------

__global__ __launch_bounds__(256) void k_bn_stats(const float* __restrict__ Hm,
                                                  float* __restrict__ ssum,
                                                  float* __restrict__ ssq) {
    int c = threadIdx.x;
    int r0 = blockIdx.x * 64;
    int r1 = min(r0 + 64, NN);
    float s = 0.f, q = 0.f;
    for (int r = r0; r < r1; ++r) {
        float v = Hm[(size_t)r * HH + c];
        s += v;
        q += v * v;
    }
    atomicAdd(&ssum[c], s);
    atomicAdd(&ssq[c], q);
}

__global__ void k_bn_final(const float* __restrict__ ssum, const float* __restrict__ ssq,
                           const float* __restrict__ gamma, const float* __restrict__ beta,
                           float* __restrict__ scale, float* __restrict__ shift) {
    int c = threadIdx.x;
    float mu = ssum[c] / (float)NN;
    float var = ssq[c] / (float)NN - mu * mu;
    float rstd = rsqrtf(var + BN_EPS);
    float sc = rstd * gamma[c];
    scale[c] = sc;
    shift[c] = beta[c] - mu * sc;
}

// T = dinv_row * relu(scale*P1 + shift)
__global__ void k_bn_apply_T(const float* __restrict__ P1, const float* __restrict__ scale,
                             const float* __restrict__ shift, const float* __restrict__ dinv,
                             float* __restrict__ T) {
    int i4 = blockIdx.x * 256 + threadIdx.x;
    if (i4 >= NN * HH / 4) return;
    int c4 = i4 & 63;
    float g = dinv[i4 >> 6];
    float4 v = reinterpret_cast<const float4*>(P1)[i4];
    float4 sc = reinterpret_cast<const float4*>(scale)[c4];
    float4 sh = reinterpret_cast<const float4*>(shift)[c4];
    v.x = g * fmaxf(v.x * sc.x + sh.x, 0.f);
    v.y = g * fmaxf(v.y * sc.y + sh.y, 0.f);
    v.z = g * fmaxf(v.z * sc.z + sh.z, 0.f);
    v.w = g * fmaxf(v.w * sc.w + sh.w, 0.f);
    reinterpret_cast<float4*>(T)[i4] = v;
}

// ---------------- edge head (dst-centric): one wave per node ----------------
// out[e] = sigmoid(relu(A[src]+B[dst]+bm1).Wm2 + bm2); B-side hoisted per node.

__global__ __launch_bounds__(256) void k_edge_csr(const short* __restrict__ Aarr,
                                                  const short* __restrict__ Barr,
                                                  const int* __restrict__ srcl,
                                                  const int* __restrict__ csr_eid,
                                                  const int* __restrict__ row_start,
                                                  const float* __restrict__ bm1,
                                                  const float* __restrict__ Wm2,
                                                  const float* __restrict__ bm2,
                                                  float* __restrict__ out) {
    int wave = threadIdx.x >> 6;
    int lane = threadIdx.x & 63;
    int n = blockIdx.x * 4 + wave;
    if (n >= NN) return;
    float4 bb = reinterpret_cast<const float4*>(bm1)[lane];
    float4 w = reinterpret_cast<const float4*>(Wm2)[lane];
    short4v bv = *(const short4v*)(Barr + (size_t)n * 256 + lane * 4);
    float b0 = bf2f(bv[0]) + bb.x, b1 = bf2f(bv[1]) + bb.y,
          b2 = bf2f(bv[2]) + bb.z, b3 = bf2f(bv[3]) + bb.w;
    float zb = bm2[0];
    int s0 = row_start[n], s1 = row_start[n + 1];
    for (int j = s0; j < s1; ++j) {
        int e = csr_eid[j];
        int s = srcl[e];
        short4v a = *(const short4v*)(Aarr + (size_t)s * 256 + lane * 4);
        float t = fmaxf(bf2f(a[0]) + b0, 0.f) * w.x
                + fmaxf(bf2f(a[1]) + b1, 0.f) * w.y
                + fmaxf(bf2f(a[2]) + b2, 0.f) * w.z
                + fmaxf(bf2f(a[3]) + b3, 0.f) * w.w;
#pragma unroll
        for (int off = 32; off; off >>= 1) t += __shfl_xor(t, off);
        if (lane == 0) out[e] = 1.0f / (1.0f + expf(-(t + zb)));
    }
}

// ---------------- launch ----------------

extern "C" void kernel_launch(void* const* d_in, const int* in_sizes, int n_in,
                              void* d_out, int out_size, void* d_ws, size_t ws_size,
                              hipStream_t stream) {
    const float* x     = (const float*)d_in[0];
    const int*   ei    = (const int*)d_in[1];
    const float* W1    = (const float*)d_in[2];
    const float* b1    = (const float*)d_in[3];
    const float* gamma = (const float*)d_in[4];
    const float* beta  = (const float*)d_in[5];
    const float* W2    = (const float*)d_in[6];
    const float* b2    = (const float*)d_in[7];
    const float* Wm1   = (const float*)d_in[8];
    const float* bm1   = (const float*)d_in[9];
    const float* Wm2   = (const float*)d_in[10];
    const float* bm2   = (const float*)d_in[11];
    float* out = (float*)d_out;
    const int* src = ei;
    const int* dst = ei + EE;

    char* ws = (char*)d_ws;
    size_t off = 0;
    auto take = [&](size_t b) -> char* {
        char* p = ws + off;
        off += (b + 255) & ~(size_t)255;
        return p;
    };
    // small tables (~3.3 MB)
    int*   deg_cnt   = (int*)take((size_t)NN * 4);
    float* dinv      = (float*)take((size_t)NN * 4);
    int*   row_start = (int*)take((size_t)(NN + 1) * 4);
    int*   cursor    = (int*)take((size_t)NN * 4);
    int*   csr_eid   = (int*)take((size_t)EE * 4);
    int*   bsum      = (int*)take((size_t)NSB * 4);
    int*   boff      = (int*)take((size_t)NSB * 4);
    float* ssum      = (float*)take(1024);
    float* ssq       = (float*)take(1024);
    float* scale     = (float*)take(1024);
    float* shift     = (float*)take(1024);
    short* W1thi     = (short*)take((size_t)128 * 256 * 2);
    short* W1tlo     = (short*)take((size_t)128 * 256 * 2);
    short* W2thi     = (short*)take((size_t)256 * 256 * 2);
    short* W2tlo     = (short*)take((size_t)256 * 256 * 2);
    short* Wcthi     = (short*)take((size_t)256 * 512 * 2);
    short* Wctlo     = (short*)take((size_t)256 * 512 * 2);
    // three 51.2 MB slots, liveness-aliased (peak ~157 MB, known to fit)
    const size_t SLOT = (size_t)NN * HH * 4;  // 51,200,000
    char* slotA = take(SLOT);
    char* slotB = take(SLOT);
    char* slotC = take(SLOT);

    short* G1hi = (short*)slotB;                    // [N,128] bf16
    short* G1lo = (short*)(slotB + 12800000);
    float* P1   = (float*)slotC;                    // [N,256] fp32
    float* T    = (float*)slotA;                    // [N,256] fp32
    short* G2hi = (short*)slotB;                    // [N,256] bf16 (G1 dead)
    short* G2lo = (short*)(slotB + 25600000);
    short* H2hi = (short*)slotC;                    // [N,256] bf16 (P1 dead)
    short* H2lo = (short*)(slotC + 25600000);
    short* Aarr = (short*)slotA;                    // [N,256] bf16 (T dead)
    short* Barr = (short*)(slotA + 25600000);
    (void)ssq; (void)ws_size;

    hipMemsetAsync(deg_cnt, 0, (size_t)NN * 4, stream);
    hipMemsetAsync(ssum, 0, 2048, stream);  // ssum + ssq adjacent

    k_count<<<(EE + 255) / 256, 256, 0, stream>>>(dst, deg_cnt);
    k_scan1<<<NSB, 256, 0, stream>>>(deg_cnt, bsum);
    k_scan2<<<1, 256, 0, stream>>>(bsum, boff, row_start);
    k_scan3<<<NSB, 256, 0, stream>>>(deg_cnt, boff, row_start, cursor, dinv);
    k_fill<<<(EE + 255) / 256, 256, 0, stream>>>(dst, cursor, csr_eid);
    k_wsplit<<<(128 * 256 + 255) / 256, 256, 0, stream>>>(W1, W1thi, W1tlo, 128, 256);
    k_wsplit<<<(256 * 256 + 255) / 256, 256, 0, stream>>>(W2, W2thi, W2tlo, 256, 256);
    k_wsplit_cat<<<(256 * 512 + 255) / 256, 256, 0, stream>>>(Wm1, Wcthi, Wctlo);

    const int MB64 = (NN + 63) / 64;  // 782
    // layer 1 (aggregate-first, scale fused)
    k_aggX<<<(NN + 3) / 4, 256, 0, stream>>>(x, src, csr_eid, row_start, dinv, G1hi, G1lo);
    gemm_stripe<128, 256, 0><<<MB64, 512, 0, stream>>>(G1hi, G1lo, W1thi, W1tlo, b1,
                                                       P1, nullptr, nullptr, nullptr, nullptr, NN);
    // batchnorm; T = dinv * relu(BN(P1))
    k_bn_stats<<<(NN + 63) / 64, 256, 0, stream>>>(P1, ssum, ssq);
    k_bn_final<<<1, 256, 0, stream>>>(ssum, ssq, gamma, beta, scale, shift);
    k_bn_apply_T<<<NN * HH / 4 / 256, 256, 0, stream>>>(P1, scale, shift, dinv, T);
    // layer 2
    k_aggH<<<(NN + 3) / 4, 256, 0, stream>>>(T, src, csr_eid, row_start, dinv, G2hi, G2lo);
    gemm_stripe<256, 256, 1><<<MB64, 512, 0, stream>>>(G2hi, G2lo, W2thi, W2tlo, b2,
                                                       nullptr, H2hi, H2lo, nullptr, nullptr, NN);
    // edge-head node factors: [Aarr | Barr] = H2 @ Wcat (bf16 out)
    gemm_stripe<256, 512, 2><<<MB64, 512, 0, stream>>>(H2hi, H2lo, Wcthi, Wctlo, nullptr,
                                                       nullptr, nullptr, nullptr, Aarr, Barr, NN);
    // edge head (dst-centric)
    k_edge_csr<<<(NN + 3) / 4, 256, 0, stream>>>(Aarr, Barr, src, csr_eid, row_start,
                                                 bm1, Wm2, bm2, out);
}